// Round 16
// baseline (952.387 us; speedup 1.0000x reference)
//
#include <hip/hip_runtime.h>
#include <hip/hip_cooperative_groups.h>
namespace cg = cooperative_groups;

typedef unsigned int u32;
typedef unsigned short u16;

#define NN 50000
#define EE 1250000
#define DD 128
#define HH 64
#define NCLS 10
#define NG 128
#define MAXDEG 80                    // Poisson(25): P(deg>=80) ~ 0

#define NTILES ((NN + 63) / 64)     // 782
#define LDSW 68                      // LDS row stride for GEMM tiles

#define PBUK 392                     // buckets = dst>>7
#define SBLK 128                     // sort chunks
#define CHUNK ((EE + SBLK - 1) / SBLK)
#define NDP  (PBUK * 128)
#define NPAIR ((NN + 1) / 2)

// Round-2: int inputs are int32. Round-3: no ReLU after GraphConv.
// Round-5/12: contended/per-element device atomics serialize -- avoid.
// Round-7..10: adjacency via per-block counting sort (full-line writes only).
// Round-14: don't fuse the latency-bound gather into the LDS-capped GEMM.
// Round-13/15: dur pinned at ~351 while kernels changed -> floor is launch
// gaps (~14us x 8 launches) + harness fills. Round-16: ONE cooperative kernel,
// phases split by grid.sync(); per-block syncthreads at phase entry since the
// end-of-kernel barrier is gone. Fallback to the 8-kernel pipeline if the
// cooperative launch is rejected.

__device__ __forceinline__ u32 f2bf(float f) {
    u32 u = __float_as_uint(f);
    return (u + 0x7FFFu + ((u >> 16) & 1u)) >> 16;
}
__device__ __forceinline__ float bf2f(u16 v) {
    return __uint_as_float(((u32)v) << 16);
}

// ---------------- tiled-GEMM building blocks ----------------

__device__ __forceinline__ void load_w(const float* __restrict__ g, float (*wS)[LDSW], int t) {
    #pragma unroll
    for (int r = 0; r < 4; ++r) {
        int idx = r * 256 + t;
        int k = idx >> 4, f4 = idx & 15;
        float4 v = *(const float4*)(g + k * 64 + f4 * 4);
        *(float4*)&wS[k][f4 * 4] = v;
    }
}

__device__ __forceinline__ void load_inT(const float* __restrict__ g, int ld, int c0,
                                         float (*iS)[LDSW], int t, int nb) {
    #pragma unroll
    for (int r = 0; r < 4; ++r) {
        int idx = r * 256 + t;
        int n = idx >> 4, k4 = idx & 15;
        int node = nb + n;
        if (node >= NN) node = NN - 1;
        float4 v = *(const float4*)(g + (size_t)node * ld + c0 + k4 * 4);
        iS[k4 * 4 + 0][n] = v.x;
        iS[k4 * 4 + 1][n] = v.y;
        iS[k4 * 4 + 2][n] = v.z;
        iS[k4 * 4 + 3][n] = v.w;
    }
}

__device__ __forceinline__ void gemm_acc(const float (*iS)[LDSW], const float (*wS)[LDSW],
                                         float acc[4][4], int tx, int ty) {
    #pragma unroll 8
    for (int k = 0; k < 64; ++k) {
        const float4 wv = *(const float4*)&wS[k][tx * 4];
        const float4 iv = *(const float4*)&iS[k][ty * 4];
        acc[0][0] += iv.x * wv.x; acc[0][1] += iv.x * wv.y; acc[0][2] += iv.x * wv.z; acc[0][3] += iv.x * wv.w;
        acc[1][0] += iv.y * wv.x; acc[1][1] += iv.y * wv.y; acc[1][2] += iv.y * wv.z; acc[1][3] += iv.y * wv.w;
        acc[2][0] += iv.z * wv.x; acc[2][1] += iv.z * wv.y; acc[2][2] += iv.z * wv.z; acc[2][3] += iv.z * wv.w;
        acc[3][0] += iv.w * wv.x; acc[3][1] += iv.w * wv.y; acc[3][2] += iv.w * wv.z; acc[3][3] += iv.w * wv.w;
    }
}

__device__ __forceinline__ void store_accT(float (*iS)[LDSW], const float acc[4][4], int tx, int ty) {
    #pragma unroll
    for (int i = 0; i < 4; ++i)
        *(float4*)&iS[tx * 4 + i][ty * 4] =
            make_float4(acc[0][i], acc[1][i], acc[2][i], acc[3][i]);
}

__device__ __forceinline__ void init_bias(float acc[4][4], const float* __restrict__ b, int tx) {
    float4 bv = *(const float4*)(b + tx * 4);
    #pragma unroll
    for (int j = 0; j < 4; ++j) { acc[j][0] = bv.x; acc[j][1] = bv.y; acc[j][2] = bv.z; acc[j][3] = bv.w; }
}

__device__ __forceinline__ void relu_acc(float acc[4][4]) {
    #pragma unroll
    for (int j = 0; j < 4; ++j)
        #pragma unroll
        for (int i = 0; i < 4; ++i) acc[j][i] = fmaxf(acc[j][i], 0.0f);
}

__device__ __forceinline__ void store_out(float* __restrict__ g, const float acc[4][4],
                                          int tx, int ty, int nb) {
    #pragma unroll
    for (int j = 0; j < 4; ++j) {
        int node = nb + ty * 4 + j;
        if (node < NN)
            *(float4*)(g + (size_t)node * HH + tx * 4) =
                make_float4(acc[j][0], acc[j][1], acc[j][2], acc[j][3]);
    }
}

__device__ __forceinline__ void store_hb(u16* __restrict__ hb, const float acc[4][4],
                                         int tx, int ty, int nb) {
    #pragma unroll
    for (int j = 0; j < 4; ++j) {
        int node = nb + ty * 4 + j;
        if (node < NN) {
            u32 p0 = f2bf(acc[j][0]) | (f2bf(acc[j][1]) << 16);
            u32 p1 = f2bf(acc[j][2]) | (f2bf(acc[j][3]) << 16);
            u32* q = (u32*)(hb + (size_t)node * HH) + tx * 2;
            q[0] = p0; q[1] = p1;
        }
    }
}

// ---------------- phase bodies (shared by coop kernel and fallback) ----------------

__device__ void psort_chunk(int cb, const int* __restrict__ ei, u32* __restrict__ bedges,
                            int* __restrict__ gboff, int* __restrict__ ghist,
                            char* smem, int t) {
    int* hist  = (int*)smem;
    int* boffS = hist + PBUK;
    int* wsum  = boffS + PBUK;
    const int base = cb * CHUNK;
    const int n = min(CHUNK, EE - base);
    __syncthreads();                      // protect smem reuse across phases
    for (int b = t; b < PBUK; b += 256) hist[b] = 0;
    __syncthreads();
    for (int i = t; i < n; i += 256) {
        int src = ei[base + i];
        int dst = ei[EE + base + i];
        if ((unsigned)src < NN && (unsigned)dst < NN)
            atomicAdd(&hist[dst >> 7], 1);
    }
    __syncthreads();
    int v = 0, h0 = 0;
    if (t < PBUK / 2) { h0 = hist[2 * t]; v = h0 + hist[2 * t + 1]; }
    int lane = t & 63, wd = t >> 6;
    int incl = v;
    #pragma unroll
    for (int d = 1; d < 64; d <<= 1) {
        int tt = __shfl_up(incl, d);
        if (lane >= d) incl += tt;
    }
    if (lane == 63) wsum[wd] = incl;
    __syncthreads();
    int woff = 0;
    for (int w = 0; w < wd; ++w) woff += wsum[w];
    if (t < PBUK / 2) {
        int excl = woff + incl - v;
        boffS[2 * t] = excl;
        boffS[2 * t + 1] = excl + h0;
    }
    __syncthreads();
    for (int b = t; b < PBUK; b += 256) {
        gboff[cb * PBUK + b] = boffS[b];
        ghist[cb * PBUK + b] = hist[b];
    }
    __syncthreads();
    for (int b = t; b < PBUK; b += 256) hist[b] = 0;
    __syncthreads();
    for (int i = t; i < n; i += 256) {
        int src = ei[base + i];
        int dst = ei[EE + base + i];
        if ((unsigned)src < NN && (unsigned)dst < NN) {
            int b = dst >> 7;
            int p = atomicAdd(&hist[b], 1);
            bedges[base + boffS[b] + p] = ((u32)src << 7) | (u32)(dst & 127);
        }
    }
}

__device__ void adj_bucket(int b, const u32* __restrict__ bedges,
                           const int* __restrict__ gboff, const int* __restrict__ ghist,
                           u16* __restrict__ slots, int* __restrict__ deg,
                           char* smem, int t) {
    u16* ls = (u16*)smem;                      // 128*80 u16 = 20480 B
    int* lc = (int*)(smem + 128 * MAXDEG * 2); // 512 B
    const int lane = t & 63, wd = t >> 6;
    __syncthreads();
    if (t < 128) lc[t] = 0;
    __syncthreads();
    for (int sb = wd; sb < SBLK; sb += 4) {
        int off = gboff[sb * PBUK + b];
        int cnt = ghist[sb * PBUK + b];
        int gbase = sb * CHUNK + off;
        for (int i = lane; i < cnt; i += 64) {
            u32 p = bedges[gbase + i];
            int o = (int)(p & 127u);
            int src = (int)(p >> 7);
            int pos = atomicAdd(&lc[o], 1);
            if (pos < MAXDEG) ls[o * MAXDEG + pos] = (u16)src;
        }
    }
    __syncthreads();
    u32* gs = (u32*)(slots + (size_t)b * 128 * MAXDEG);
    const u32* lsu = (const u32*)ls;
    for (int i = t; i < 128 * MAXDEG / 2; i += 256) gs[i] = lsu[i];
    if (t < 128) deg[b * 128 + t] = lc[t];
}

__device__ void embed_tile(int tile, const float* __restrict__ x,
                           const float* __restrict__ w1, const float* __restrict__ b1,
                           const float* __restrict__ w2, const float* __restrict__ b2,
                           float* __restrict__ h, u16* __restrict__ hb,
                           float (*wS)[LDSW], float (*iS)[LDSW], int t) {
    const int tx = t & 15, ty = t >> 4;
    const int nb = tile * 64;
    __syncthreads();                      // protect smem reuse across iterations
    float acc[4][4];
    init_bias(acc, b1, tx);
    load_w(w1, wS, t);
    load_inT(x, DD, 0, iS, t, nb);
    __syncthreads();
    gemm_acc(iS, wS, acc, tx, ty);
    __syncthreads();
    load_w(w1 + 64 * 64, wS, t);
    load_inT(x, DD, 64, iS, t, nb);
    __syncthreads();
    gemm_acc(iS, wS, acc, tx, ty);
    __syncthreads();
    relu_acc(acc);
    store_accT(iS, acc, tx, ty);
    load_w(w2, wS, t);
    __syncthreads();
    float acc2[4][4];
    init_bias(acc2, b2, tx);
    gemm_acc(iS, wS, acc2, tx, ty);
    store_out(h, acc2, tx, ty, nb);
    store_hb(hb, acc2, tx, ty, nb);
}

__device__ void dense_tile(int tile, float* __restrict__ h, const float* __restrict__ agg,
                           const float* __restrict__ relw, const float* __restrict__ relb,
                           const float* __restrict__ rootw,
                           const float* __restrict__ pw1, const float* __restrict__ pb1,
                           const float* __restrict__ pw2, const float* __restrict__ pb2,
                           u16* __restrict__ hb, int do_hb,
                           float (*wS)[LDSW], float (*iS)[LDSW], int t) {
    const int tx = t & 15, ty = t >> 4;
    const int nb = tile * 64;
    __syncthreads();
    float acc[4][4];
    init_bias(acc, relb, tx);
    load_w(relw, wS, t);
    load_inT(agg, HH, 0, iS, t, nb);
    __syncthreads();
    gemm_acc(iS, wS, acc, tx, ty);
    __syncthreads();
    load_w(rootw, wS, t);
    load_inT(h, HH, 0, iS, t, nb);
    __syncthreads();
    gemm_acc(iS, wS, acc, tx, ty);
    __syncthreads();
    store_accT(iS, acc, tx, ty);
    load_w(pw1, wS, t);
    __syncthreads();
    float acc2[4][4];
    init_bias(acc2, pb1, tx);
    gemm_acc(iS, wS, acc2, tx, ty);
    relu_acc(acc2);
    __syncthreads();
    store_accT(iS, acc2, tx, ty);
    load_w(pw2, wS, t);
    __syncthreads();
    float acc3[4][4];
    init_bias(acc3, pb2, tx);
    gemm_acc(iS, wS, acc3, tx, ty);
    relu_acc(acc3);
    store_out(h, acc3, tx, ty, nb);
    if (do_hb) store_hb(hb, acc3, tx, ty, nb);
}

__device__ void agg_pair(int nA, const u16* __restrict__ hb, const int* __restrict__ deg,
                         const u16* __restrict__ slots, float* __restrict__ agg, int lane) {
    if (nA >= NN) return;
    const int nB = nA + 1;
    const int dA = deg[nA];
    const int dB = (nB < NN) ? deg[nB] : 0;
    const int mA = min(dA, MAXDEG), mB = min(dB, MAXDEG);
    const u16* srA = slots + (size_t)nA * MAXDEG;
    const u16* srB = slots + (size_t)nB * MAXDEG;
    const u32* rowA = (const u32*)srA;
    const u32* rowB = (const u32*)srB;
    float sA = 0.0f, sB = 0.0f;
    const int mm = max(mA, mB);
    for (int e = 0; e + 8 <= mm; e += 8) {
        const int hx = e >> 1;
        const bool pA = (e + 8 <= mA), pB = (e + 8 <= mB);
        float a0=0,a1=0,a2=0,a3=0,a4=0,a5=0,a6=0,a7=0;
        float b0=0,b1=0,b2=0,b3=0,b4=0,b5=0,b6=0,b7=0;
        if (pA) {
            u32 u0 = rowA[hx], u1 = rowA[hx+1], u2 = rowA[hx+2], u3 = rowA[hx+3];
            a0 = bf2f(hb[(size_t)(u0 & 0xffffu) * HH + lane]);
            a1 = bf2f(hb[(size_t)(u0 >> 16) * HH + lane]);
            a2 = bf2f(hb[(size_t)(u1 & 0xffffu) * HH + lane]);
            a3 = bf2f(hb[(size_t)(u1 >> 16) * HH + lane]);
            a4 = bf2f(hb[(size_t)(u2 & 0xffffu) * HH + lane]);
            a5 = bf2f(hb[(size_t)(u2 >> 16) * HH + lane]);
            a6 = bf2f(hb[(size_t)(u3 & 0xffffu) * HH + lane]);
            a7 = bf2f(hb[(size_t)(u3 >> 16) * HH + lane]);
        }
        if (pB) {
            u32 u0 = rowB[hx], u1 = rowB[hx+1], u2 = rowB[hx+2], u3 = rowB[hx+3];
            b0 = bf2f(hb[(size_t)(u0 & 0xffffu) * HH + lane]);
            b1 = bf2f(hb[(size_t)(u0 >> 16) * HH + lane]);
            b2 = bf2f(hb[(size_t)(u1 & 0xffffu) * HH + lane]);
            b3 = bf2f(hb[(size_t)(u1 >> 16) * HH + lane]);
            b4 = bf2f(hb[(size_t)(u2 & 0xffffu) * HH + lane]);
            b5 = bf2f(hb[(size_t)(u2 >> 16) * HH + lane]);
            b6 = bf2f(hb[(size_t)(u3 & 0xffffu) * HH + lane]);
            b7 = bf2f(hb[(size_t)(u3 >> 16) * HH + lane]);
        }
        if (pA) sA += ((a0 + a1) + (a2 + a3)) + ((a4 + a5) + (a6 + a7));
        if (pB) sB += ((b0 + b1) + (b2 + b3)) + ((b4 + b5) + (b6 + b7));
    }
    for (int e = mA & ~7; e < mA; ++e)
        sA += bf2f(hb[(size_t)srA[e] * HH + lane]);
    for (int e = mB & ~7; e < mB; ++e)
        sB += bf2f(hb[(size_t)srB[e] * HH + lane]);
    agg[(size_t)nA * HH + lane] = sA * (1.0f / (float)max(dA, 1));
    if (nB < NN)
        agg[(size_t)nB * HH + lane] = sB * (1.0f / (float)max(dB, 1));
}

__device__ void poolcls_group(int g, const float* __restrict__ h, const int* __restrict__ batch,
                              const float* __restrict__ w, const float* __restrict__ b,
                              float* __restrict__ out, char* smem, int t) {
    float* red  = (float*)smem;          // [4][LDSW]
    float* prow = red + 4 * LDSW;        // [HH]
    const int lane = t & 63, wd = t >> 6;
    int lo = 0, hi = NN;
    while (lo < hi) { int mid = (lo + hi) >> 1; if (batch[mid] < g) lo = mid + 1; else hi = mid; }
    const int beg = lo;
    lo = 0; hi = NN;
    while (lo < hi) { int mid = (lo + hi) >> 1; if (batch[mid] < g + 1) lo = mid + 1; else hi = mid; }
    const int end = lo;
    float acc = 0.0f;
    for (int n = beg + wd; n < end; n += 4)
        acc += h[(size_t)n * HH + lane];
    __syncthreads();                      // protect smem reuse
    red[wd * LDSW + lane] = acc;
    __syncthreads();
    if (wd == 0) {
        float s = red[0 * LDSW + lane] + red[1 * LDSW + lane] +
                  red[2 * LDSW + lane] + red[3 * LDSW + lane];
        float inv = 1.0f / (float)max(end - beg, 1);
        prow[lane] = s * inv;
    }
    __syncthreads();
    if (t < NCLS) {
        float o = b[t];
        #pragma unroll 8
        for (int k = 0; k < HH; ++k) o += prow[k] * w[k * NCLS + t];
        out[g * NCLS + t] = o;
    }
}

// ---------------- single cooperative mega-kernel ----------------

struct KP {
    const float* x; const int* ei; const int* batch;
    const float *emb_w1, *emb_b1, *emb_w2, *emb_b2;
    const float *rel_w, *rel_b, *root_w, *pw1, *pb1, *pw2, *pb2;
    const float *cls_w, *cls_b;
    float* out;
    float* h; u16* hb; float* agg; u32* bedges; u16* slots;
    int* deg; int* gboff; int* ghist;
};

__global__ __launch_bounds__(256, 4) void k_all(KP p) {
    cg::grid_group grid = cg::this_grid();
    __shared__ __align__(16) char smem[2 * 64 * LDSW * 4];   // 34816 B
    float (*wS)[LDSW] = (float (*)[LDSW])smem;
    float (*iS)[LDSW] = (float (*)[LDSW])(smem + 64 * LDSW * 4);
    const int t = threadIdx.x;
    const int GB = gridDim.x;
    const int lane = t & 63, wd = t >> 6;

    // phase A: embedding tiles (independent) + edge counting-sort chunks
    for (int tile = blockIdx.x; tile < NTILES; tile += GB)
        embed_tile(tile, p.x, p.emb_w1, p.emb_b1, p.emb_w2, p.emb_b2, p.h, p.hb, wS, iS, t);
    for (int cb = blockIdx.x; cb < SBLK; cb += GB)
        psort_chunk(cb, p.ei, p.bedges, p.gboff, p.ghist, smem, t);
    grid.sync();
    // phase B: adjacency build
    for (int b = blockIdx.x; b < PBUK; b += GB)
        adj_bucket(b, p.bedges, p.gboff, p.ghist, p.slots, p.deg, smem, t);
    grid.sync();
    // layer 0: gather (bedges alias now dead) then conv/MLP
    for (int u = blockIdx.x * 4 + wd; u < NPAIR; u += GB * 4)
        agg_pair(2 * u, p.hb, p.deg, p.slots, p.agg, lane);
    grid.sync();
    for (int tile = blockIdx.x; tile < NTILES; tile += GB)
        dense_tile(tile, p.h, p.agg, p.rel_w, p.rel_b, p.root_w,
                   p.pw1, p.pb1, p.pw2, p.pb2, p.hb, 1, wS, iS, t);
    grid.sync();
    // layer 1
    for (int u = blockIdx.x * 4 + wd; u < NPAIR; u += GB * 4)
        agg_pair(2 * u, p.hb, p.deg, p.slots, p.agg, lane);
    grid.sync();
    for (int tile = blockIdx.x; tile < NTILES; tile += GB)
        dense_tile(tile, p.h, p.agg, p.rel_w + HH * HH, p.rel_b + HH, p.root_w + HH * HH,
                   p.pw1 + HH * HH, p.pb1 + HH, p.pw2 + HH * HH, p.pb2 + HH,
                   p.hb, 0, wS, iS, t);
    grid.sync();
    // pooled mean + classifier
    for (int g = blockIdx.x; g < NG; g += GB)
        poolcls_group(g, p.h, p.batch, p.cls_w, p.cls_b, p.out, smem, t);
}

// ---------------- fallback standalone kernels (round-15 pipeline) ----------------

__global__ __launch_bounds__(256) void k_psort(const int* ei, u32* bedges, int* gboff, int* ghist) {
    __shared__ __align__(16) char smem[(2 * PBUK + 4) * 4];
    psort_chunk(blockIdx.x, ei, bedges, gboff, ghist, smem, threadIdx.x);
}
__global__ __launch_bounds__(256) void k_adj(const u32* bedges, const int* gboff, const int* ghist,
                                             u16* slots, int* deg) {
    __shared__ __align__(16) char smem[128 * MAXDEG * 2 + 512];
    adj_bucket(blockIdx.x, bedges, gboff, ghist, slots, deg, smem, threadIdx.x);
}
__global__ __launch_bounds__(256) void k_embed(const float* x, const float* w1, const float* b1,
                                               const float* w2, const float* b2,
                                               float* h, u16* hb) {
    __shared__ __align__(16) char smem[2 * 64 * LDSW * 4];
    embed_tile(blockIdx.x, x, w1, b1, w2, b2, h, hb,
               (float (*)[LDSW])smem, (float (*)[LDSW])(smem + 64 * LDSW * 4), threadIdx.x);
}
__global__ __launch_bounds__(256) void k_agg(const u16* hb, const int* deg, const u16* slots,
                                             float* agg) {
    int u = blockIdx.x * 4 + (threadIdx.x >> 6);
    if (u < NPAIR) agg_pair(2 * u, hb, deg, slots, agg, threadIdx.x & 63);
}
__global__ __launch_bounds__(256) void k_dense(float* h, const float* agg,
                                               const float* relw, const float* relb, const float* rootw,
                                               const float* pw1, const float* pb1,
                                               const float* pw2, const float* pb2,
                                               u16* hb, int do_hb) {
    __shared__ __align__(16) char smem[2 * 64 * LDSW * 4];
    dense_tile(blockIdx.x, h, agg, relw, relb, rootw, pw1, pb1, pw2, pb2, hb, do_hb,
               (float (*)[LDSW])smem, (float (*)[LDSW])(smem + 64 * LDSW * 4), threadIdx.x);
}
__global__ __launch_bounds__(256) void k_poolcls(const float* h, const int* batch,
                                                 const float* w, const float* b, float* out) {
    __shared__ __align__(16) char smem[(4 * LDSW + HH) * 4];
    poolcls_group(blockIdx.x, h, batch, w, b, out, smem, threadIdx.x);
}

// ---------------- Launch ----------------

extern "C" void kernel_launch(void* const* d_in, const int* in_sizes, int n_in,
                              void* d_out, int out_size, void* d_ws, size_t ws_size,
                              hipStream_t stream) {
    KP p;
    p.x      = (const float*)d_in[0];
    p.ei     = (const int*)d_in[1];
    p.batch  = (const int*)d_in[2];
    p.emb_w1 = (const float*)d_in[3];
    p.emb_b1 = (const float*)d_in[4];
    p.emb_w2 = (const float*)d_in[5];
    p.emb_b2 = (const float*)d_in[6];
    p.rel_w  = (const float*)d_in[7];
    p.rel_b  = (const float*)d_in[8];
    p.root_w = (const float*)d_in[9];
    p.pw1    = (const float*)d_in[10];
    p.pb1    = (const float*)d_in[11];
    p.pw2    = (const float*)d_in[12];
    p.pb2    = (const float*)d_in[13];
    p.cls_w  = (const float*)d_in[14];
    p.cls_b  = (const float*)d_in[15];
    p.out    = (float*)d_out;

    char* ws = (char*)d_ws;
    size_t off = 0;
    auto alloc = [&](size_t bytes) -> void* {
        off = (off + 255) & ~(size_t)255;
        void* q = ws + off;
        off += bytes;
        return q;
    };
    p.h      = (float*)alloc((size_t)NN * HH * 4);
    p.hb     = (u16*)alloc((size_t)NN * HH * 2);
    p.agg    = (float*)alloc((size_t)NN * HH * 4);
    p.bedges = (u32*)p.agg;            // alias: bedges dead before agg L0 writes (grid sync between)
    p.slots  = (u16*)alloc((size_t)NDP * MAXDEG * 2);
    p.deg    = (int*)alloc((size_t)NDP * 4);
    p.gboff  = (int*)alloc((size_t)SBLK * PBUK * 4);
    p.ghist  = (int*)alloc((size_t)SBLK * PBUK * 4);

    int nb = 0;
    hipError_t qerr = hipOccupancyMaxActiveBlocksPerMultiprocessor(&nb, k_all, 256, 0);
    if (qerr != hipSuccess || nb < 1) nb = 2;
    int GB = nb * 256;
    if (GB > 1024) GB = 1024;

    void* kargs[] = { (void*)&p };
    hipError_t err = hipLaunchCooperativeKernel(k_all, dim3(GB), dim3(256), kargs, 0, stream);

    if (err != hipSuccess) {
        // fallback: proven 8-launch pipeline (identical math)
        k_psort<<<SBLK, 256, 0, stream>>>(p.ei, p.bedges, p.gboff, p.ghist);
        k_adj<<<PBUK, 256, 0, stream>>>(p.bedges, p.gboff, p.ghist, p.slots, p.deg);
        k_embed<<<NTILES, 256, 0, stream>>>(p.x, p.emb_w1, p.emb_b1, p.emb_w2, p.emb_b2, p.h, p.hb);
        k_agg<<<(NPAIR + 3) / 4, 256, 0, stream>>>(p.hb, p.deg, p.slots, p.agg);
        k_dense<<<NTILES, 256, 0, stream>>>(p.h, p.agg, p.rel_w, p.rel_b, p.root_w,
                                            p.pw1, p.pb1, p.pw2, p.pb2, p.hb, 1);
        k_agg<<<(NPAIR + 3) / 4, 256, 0, stream>>>(p.hb, p.deg, p.slots, p.agg);
        k_dense<<<NTILES, 256, 0, stream>>>(p.h, p.agg,
                                            p.rel_w + HH * HH, p.rel_b + HH, p.root_w + HH * HH,
                                            p.pw1 + HH * HH, p.pb1 + HH, p.pw2 + HH * HH, p.pb2 + HH,
                                            p.hb, 0);
        k_poolcls<<<NG, 256, 0, stream>>>(p.h, p.batch, p.cls_w, p.cls_b, p.out);
    }
}

// Round 17
// 335.570 us; speedup vs baseline: 2.8381x; 2.8381x over previous
//
#include <hip/hip_runtime.h>

typedef unsigned int u32;
typedef unsigned short u16;

#define NN 50000
#define EE 1250000
#define DD 128
#define HH 64
#define NCLS 10
#define NG 128
#define MAXDEG 80                    // Poisson(25): P(deg>=80) ~ 0

#define NTILES ((NN + 63) / 64)     // 782
#define LDSW 68                      // LDS row stride for GEMM tiles

#define PBUK 392                     // buckets = dst>>7
#define SBLK 128                     // sort chunks
#define CHUNK ((EE + SBLK - 1) / SBLK)  // 9766
#define NDP  (PBUK * 128)            // 50176
#define NPAIR ((NN + 1) / 2)

// Round-2: int inputs are int32. ei int32 [2,E]: src=ei[e], dst=ei[EE+e].
// Round-3: no ReLU between GraphConv out and post-MLP.
// Round-4: 4x4-per-thread LDS-tiled GEMMs.
// Round-5/12: contended/per-element device atomics serialize at the coherence point.
// Round-7..10: adjacency via per-block counting sort (full-line writes only).
// Round-14: don't fuse the latency-bound gather into the LDS-capped GEMM.
// Round-16 REGRESSION (reverted): cooperative mega-kernel. grid.sync() on 8
// non-coherent XCDs = system-scope fence -> L2 flushed every phase (FETCH 100->145MB),
// and one grid size strangled the gather (4096 waves vs 25000). 878us. Coop
// barriers are NOT cheap on chiplet CDNA4; keep the split pipeline.
// Round-17: round-15 pipeline, with embed+psort (independent) merged into one
// launch by block-range partition. 8 -> 7 launches.

__device__ __forceinline__ u32 f2bf(float f) {           // RNE fp32->bf16
    u32 u = __float_as_uint(f);
    return (u + 0x7FFFu + ((u >> 16) & 1u)) >> 16;
}
__device__ __forceinline__ float bf2f(u16 v) {
    return __uint_as_float(((u32)v) << 16);
}

// ---------------- tiled-GEMM building blocks ----------------

__device__ __forceinline__ void load_w(const float* __restrict__ g, float (*wS)[LDSW], int t) {
    #pragma unroll
    for (int r = 0; r < 4; ++r) {
        int idx = r * 256 + t;
        int k = idx >> 4, f4 = idx & 15;
        float4 v = *(const float4*)(g + k * 64 + f4 * 4);
        *(float4*)&wS[k][f4 * 4] = v;
    }
}

__device__ __forceinline__ void load_inT(const float* __restrict__ g, int ld, int c0,
                                         float (*iS)[LDSW], int t, int nb) {
    #pragma unroll
    for (int r = 0; r < 4; ++r) {
        int idx = r * 256 + t;
        int n = idx >> 4, k4 = idx & 15;
        int node = nb + n;
        if (node >= NN) node = NN - 1;
        float4 v = *(const float4*)(g + (size_t)node * ld + c0 + k4 * 4);
        iS[k4 * 4 + 0][n] = v.x;
        iS[k4 * 4 + 1][n] = v.y;
        iS[k4 * 4 + 2][n] = v.z;
        iS[k4 * 4 + 3][n] = v.w;
    }
}

__device__ __forceinline__ void gemm_acc(const float (*iS)[LDSW], const float (*wS)[LDSW],
                                         float acc[4][4], int tx, int ty) {
    #pragma unroll 8
    for (int k = 0; k < 64; ++k) {
        const float4 wv = *(const float4*)&wS[k][tx * 4];
        const float4 iv = *(const float4*)&iS[k][ty * 4];
        acc[0][0] += iv.x * wv.x; acc[0][1] += iv.x * wv.y; acc[0][2] += iv.x * wv.z; acc[0][3] += iv.x * wv.w;
        acc[1][0] += iv.y * wv.x; acc[1][1] += iv.y * wv.y; acc[1][2] += iv.y * wv.z; acc[1][3] += iv.y * wv.w;
        acc[2][0] += iv.z * wv.x; acc[2][1] += iv.z * wv.y; acc[2][2] += iv.z * wv.z; acc[2][3] += iv.z * wv.w;
        acc[3][0] += iv.w * wv.x; acc[3][1] += iv.w * wv.y; acc[3][2] += iv.w * wv.z; acc[3][3] += iv.w * wv.w;
    }
}

__device__ __forceinline__ void store_accT(float (*iS)[LDSW], const float acc[4][4], int tx, int ty) {
    #pragma unroll
    for (int i = 0; i < 4; ++i)
        *(float4*)&iS[tx * 4 + i][ty * 4] =
            make_float4(acc[0][i], acc[1][i], acc[2][i], acc[3][i]);
}

__device__ __forceinline__ void init_bias(float acc[4][4], const float* __restrict__ b, int tx) {
    float4 bv = *(const float4*)(b + tx * 4);
    #pragma unroll
    for (int j = 0; j < 4; ++j) { acc[j][0] = bv.x; acc[j][1] = bv.y; acc[j][2] = bv.z; acc[j][3] = bv.w; }
}

__device__ __forceinline__ void relu_acc(float acc[4][4]) {
    #pragma unroll
    for (int j = 0; j < 4; ++j)
        #pragma unroll
        for (int i = 0; i < 4; ++i) acc[j][i] = fmaxf(acc[j][i], 0.0f);
}

__device__ __forceinline__ void store_out(float* __restrict__ g, const float acc[4][4],
                                          int tx, int ty, int nb) {
    #pragma unroll
    for (int j = 0; j < 4; ++j) {
        int node = nb + ty * 4 + j;
        if (node < NN)
            *(float4*)(g + (size_t)node * HH + tx * 4) =
                make_float4(acc[j][0], acc[j][1], acc[j][2], acc[j][3]);
    }
}

__device__ __forceinline__ void store_hb(u16* __restrict__ hb, const float acc[4][4],
                                         int tx, int ty, int nb) {
    #pragma unroll
    for (int j = 0; j < 4; ++j) {
        int node = nb + ty * 4 + j;
        if (node < NN) {
            u32 p0 = f2bf(acc[j][0]) | (f2bf(acc[j][1]) << 16);
            u32 p1 = f2bf(acc[j][2]) | (f2bf(acc[j][3]) << 16);
            u32* q = (u32*)(hb + (size_t)node * HH) + tx * 2;
            q[0] = p0; q[1] = p1;
        }
    }
}

// ---------------- merged launch 1: embed tiles + psort chunks (independent) ----------------

__global__ __launch_bounds__(256) void k_embed_psort(
    const float* __restrict__ x,
    const float* __restrict__ w1, const float* __restrict__ b1,
    const float* __restrict__ w2, const float* __restrict__ b2,
    float* __restrict__ h, u16* __restrict__ hb,
    const int* __restrict__ ei, u32* __restrict__ bedges,
    int* __restrict__ gboff, int* __restrict__ ghist) {
    __shared__ __align__(16) char smem[2 * 64 * LDSW * 4];   // 34816 B (max of both paths)
    const int t = threadIdx.x;

    if (blockIdx.x < NTILES) {
        // ---- embed path ----
        float (*wS)[LDSW] = (float (*)[LDSW])smem;
        float (*iS)[LDSW] = (float (*)[LDSW])(smem + 64 * LDSW * 4);
        const int tx = t & 15, ty = t >> 4;
        const int nb = blockIdx.x * 64;

        float acc[4][4];
        init_bias(acc, b1, tx);
        load_w(w1, wS, t);
        load_inT(x, DD, 0, iS, t, nb);
        __syncthreads();
        gemm_acc(iS, wS, acc, tx, ty);
        __syncthreads();
        load_w(w1 + 64 * 64, wS, t);
        load_inT(x, DD, 64, iS, t, nb);
        __syncthreads();
        gemm_acc(iS, wS, acc, tx, ty);
        __syncthreads();
        relu_acc(acc);
        store_accT(iS, acc, tx, ty);
        load_w(w2, wS, t);
        __syncthreads();
        float acc2[4][4];
        init_bias(acc2, b2, tx);
        gemm_acc(iS, wS, acc2, tx, ty);
        store_out(h, acc2, tx, ty, nb);
        store_hb(hb, acc2, tx, ty, nb);
    } else {
        // ---- psort path (counting sort of one edge chunk) ----
        int* hist  = (int*)smem;
        int* boffS = hist + PBUK;
        int* wsum  = boffS + PBUK;
        const int cb = blockIdx.x - NTILES;
        const int base = cb * CHUNK;
        const int n = min(CHUNK, EE - base);

        for (int b = t; b < PBUK; b += 256) hist[b] = 0;
        __syncthreads();
        for (int i = t; i < n; i += 256) {
            int src = ei[base + i];
            int dst = ei[EE + base + i];
            if ((unsigned)src < NN && (unsigned)dst < NN)
                atomicAdd(&hist[dst >> 7], 1);
        }
        __syncthreads();
        int v = 0, h0 = 0;
        if (t < PBUK / 2) { h0 = hist[2 * t]; v = h0 + hist[2 * t + 1]; }
        int lane = t & 63, wd = t >> 6;
        int incl = v;
        #pragma unroll
        for (int d = 1; d < 64; d <<= 1) {
            int tt = __shfl_up(incl, d);
            if (lane >= d) incl += tt;
        }
        if (lane == 63) wsum[wd] = incl;
        __syncthreads();
        int woff = 0;
        for (int w = 0; w < wd; ++w) woff += wsum[w];
        if (t < PBUK / 2) {
            int excl = woff + incl - v;
            boffS[2 * t] = excl;
            boffS[2 * t + 1] = excl + h0;
        }
        __syncthreads();
        for (int b = t; b < PBUK; b += 256) {
            gboff[cb * PBUK + b] = boffS[b];
            ghist[cb * PBUK + b] = hist[b];
        }
        __syncthreads();
        for (int b = t; b < PBUK; b += 256) hist[b] = 0;
        __syncthreads();
        for (int i = t; i < n; i += 256) {
            int src = ei[base + i];
            int dst = ei[EE + base + i];
            if ((unsigned)src < NN && (unsigned)dst < NN) {
                int b = dst >> 7;
                int p = atomicAdd(&hist[b], 1);
                bedges[base + boffS[b] + p] = ((u32)src << 7) | (u32)(dst & 127);
            }
        }
    }
}

// ---------------- adjacency build: per-bucket in LDS ----------------

__global__ __launch_bounds__(256) void k_adj(const u32* __restrict__ bedges,
                                             const int* __restrict__ gboff,
                                             const int* __restrict__ ghist,
                                             u16* __restrict__ slots,
                                             int* __restrict__ deg) {
    __shared__ u16 ls[128 * MAXDEG];   // 20 KB
    __shared__ int lc[128];
    const int b = blockIdx.x, t = threadIdx.x;
    const int lane = t & 63, wid = t >> 6;
    if (t < 128) lc[t] = 0;
    __syncthreads();
    for (int sb = wid; sb < SBLK; sb += 4) {
        int off = gboff[sb * PBUK + b];
        int cnt = ghist[sb * PBUK + b];
        int gbase = sb * CHUNK + off;
        for (int i = lane; i < cnt; i += 64) {
            u32 p = bedges[gbase + i];
            int o = (int)(p & 127u);
            int src = (int)(p >> 7);
            int pos = atomicAdd(&lc[o], 1);
            if (pos < MAXDEG) ls[o * MAXDEG + pos] = (u16)src;
        }
    }
    __syncthreads();
    u32* gs = (u32*)(slots + (size_t)b * 128 * MAXDEG);
    const u32* lsu = (const u32*)ls;
    for (int i = t; i < 128 * MAXDEG / 2; i += 256) gs[i] = lsu[i];
    if (t < 128) deg[b * 128 + t] = lc[t];
}

// ---------------- Mean aggregation: 2 nodes/wave, 16 gathers in flight ----------------

__global__ __launch_bounds__(256) void k_agg(
    const u16* __restrict__ hb, const int* __restrict__ deg,
    const u16* __restrict__ slots, float* __restrict__ agg) {
    const int wid = threadIdx.x >> 6, lane = threadIdx.x & 63;
    const int nA = blockIdx.x * 8 + wid * 2;
    if (nA >= NN) return;
    const int nB = nA + 1;
    const int dA = deg[nA];
    const int dB = (nB < NN) ? deg[nB] : 0;
    const int mA = min(dA, MAXDEG), mB = min(dB, MAXDEG);
    const u16* srA = slots + (size_t)nA * MAXDEG;
    const u16* srB = slots + (size_t)nB * MAXDEG;
    const u32* rowA = (const u32*)srA;
    const u32* rowB = (const u32*)srB;
    float sA = 0.0f, sB = 0.0f;
    const int mm = max(mA, mB);
    for (int e = 0; e + 8 <= mm; e += 8) {
        const int hx = e >> 1;
        const bool pA = (e + 8 <= mA), pB = (e + 8 <= mB);   // wave-uniform
        float a0=0,a1=0,a2=0,a3=0,a4=0,a5=0,a6=0,a7=0;
        float b0=0,b1=0,b2=0,b3=0,b4=0,b5=0,b6=0,b7=0;
        if (pA) {
            u32 u0 = rowA[hx], u1 = rowA[hx+1], u2 = rowA[hx+2], u3 = rowA[hx+3];
            a0 = bf2f(hb[(size_t)(u0 & 0xffffu) * HH + lane]);
            a1 = bf2f(hb[(size_t)(u0 >> 16) * HH + lane]);
            a2 = bf2f(hb[(size_t)(u1 & 0xffffu) * HH + lane]);
            a3 = bf2f(hb[(size_t)(u1 >> 16) * HH + lane]);
            a4 = bf2f(hb[(size_t)(u2 & 0xffffu) * HH + lane]);
            a5 = bf2f(hb[(size_t)(u2 >> 16) * HH + lane]);
            a6 = bf2f(hb[(size_t)(u3 & 0xffffu) * HH + lane]);
            a7 = bf2f(hb[(size_t)(u3 >> 16) * HH + lane]);
        }
        if (pB) {
            u32 u0 = rowB[hx], u1 = rowB[hx+1], u2 = rowB[hx+2], u3 = rowB[hx+3];
            b0 = bf2f(hb[(size_t)(u0 & 0xffffu) * HH + lane]);
            b1 = bf2f(hb[(size_t)(u0 >> 16) * HH + lane]);
            b2 = bf2f(hb[(size_t)(u1 & 0xffffu) * HH + lane]);
            b3 = bf2f(hb[(size_t)(u1 >> 16) * HH + lane]);
            b4 = bf2f(hb[(size_t)(u2 & 0xffffu) * HH + lane]);
            b5 = bf2f(hb[(size_t)(u2 >> 16) * HH + lane]);
            b6 = bf2f(hb[(size_t)(u3 & 0xffffu) * HH + lane]);
            b7 = bf2f(hb[(size_t)(u3 >> 16) * HH + lane]);
        }
        if (pA) sA += ((a0 + a1) + (a2 + a3)) + ((a4 + a5) + (a6 + a7));
        if (pB) sB += ((b0 + b1) + (b2 + b3)) + ((b4 + b5) + (b6 + b7));
    }
    for (int e = mA & ~7; e < mA; ++e)
        sA += bf2f(hb[(size_t)srA[e] * HH + lane]);
    for (int e = mB & ~7; e < mB; ++e)
        sB += bf2f(hb[(size_t)srB[e] * HH + lane]);
    agg[(size_t)nA * HH + lane] = sA * (1.0f / (float)max(dA, 1));
    if (nB < NN)
        agg[(size_t)nB * HH + lane] = sB * (1.0f / (float)max(dB, 1));
}

// ---------------- Dense per-layer (tiled, in-place on h) ----------------

__global__ __launch_bounds__(256) void k_dense(
    float* __restrict__ h, const float* __restrict__ agg,
    const float* __restrict__ relw, const float* __restrict__ relb,
    const float* __restrict__ rootw,
    const float* __restrict__ pw1, const float* __restrict__ pb1,
    const float* __restrict__ pw2, const float* __restrict__ pb2,
    u16* __restrict__ hb, int do_hb) {
    __shared__ float wS[64][LDSW];
    __shared__ float iS[64][LDSW];
    const int t = threadIdx.x;
    const int tx = t & 15, ty = t >> 4;
    const int nb = blockIdx.x * 64;

    float acc[4][4];
    init_bias(acc, relb, tx);

    load_w(relw, wS, t);
    load_inT(agg, HH, 0, iS, t, nb);
    __syncthreads();
    gemm_acc(iS, wS, acc, tx, ty);
    __syncthreads();
    load_w(rootw, wS, t);
    load_inT(h, HH, 0, iS, t, nb);
    __syncthreads();
    gemm_acc(iS, wS, acc, tx, ty);
    __syncthreads();
    store_accT(iS, acc, tx, ty);
    load_w(pw1, wS, t);
    __syncthreads();
    float acc2[4][4];
    init_bias(acc2, pb1, tx);
    gemm_acc(iS, wS, acc2, tx, ty);
    relu_acc(acc2);
    __syncthreads();
    store_accT(iS, acc2, tx, ty);
    load_w(pw2, wS, t);
    __syncthreads();
    float acc3[4][4];
    init_bias(acc3, pb2, tx);
    gemm_acc(iS, wS, acc3, tx, ty);
    relu_acc(acc3);
    store_out(h, acc3, tx, ty, nb);
    if (do_hb) store_hb(hb, acc3, tx, ty, nb);
}

// ---------------- Fused pooling + classifier (batch sorted) ----------------

__global__ __launch_bounds__(256) void k_poolcls(
    const float* __restrict__ h, const int* __restrict__ batch,
    const float* __restrict__ w, const float* __restrict__ b,
    float* __restrict__ out) {
    const int g = blockIdx.x;
    const int t = threadIdx.x;
    const int lane = t & 63, wid = t >> 6;
    int lo = 0, hi = NN;
    while (lo < hi) { int mid = (lo + hi) >> 1; if (batch[mid] < g) lo = mid + 1; else hi = mid; }
    const int beg = lo;
    lo = 0; hi = NN;
    while (lo < hi) { int mid = (lo + hi) >> 1; if (batch[mid] < g + 1) lo = mid + 1; else hi = mid; }
    const int end = lo;

    float acc = 0.0f;
    for (int n = beg + wid; n < end; n += 4)
        acc += h[(size_t)n * HH + lane];
    __shared__ float red[4][LDSW];
    __shared__ float prow[HH];
    red[wid][lane] = acc;
    __syncthreads();
    if (wid == 0) {
        float s = red[0][lane] + red[1][lane] + red[2][lane] + red[3][lane];
        float inv = 1.0f / (float)max(end - beg, 1);
        prow[lane] = s * inv;
    }
    __syncthreads();
    if (t < NCLS) {
        float o = b[t];
        #pragma unroll 8
        for (int k = 0; k < HH; ++k) o += prow[k] * w[k * NCLS + t];
        out[g * NCLS + t] = o;
    }
}

// ---------------- Launch ----------------

extern "C" void kernel_launch(void* const* d_in, const int* in_sizes, int n_in,
                              void* d_out, int out_size, void* d_ws, size_t ws_size,
                              hipStream_t stream) {
    const float* x      = (const float*)d_in[0];
    const int*   ei     = (const int*)d_in[1];    // int32 [2,E]
    const int*   batch  = (const int*)d_in[2];    // int32 [N], sorted
    const float* emb_w1 = (const float*)d_in[3];
    const float* emb_b1 = (const float*)d_in[4];
    const float* emb_w2 = (const float*)d_in[5];
    const float* emb_b2 = (const float*)d_in[6];
    const float* rel_w  = (const float*)d_in[7];
    const float* rel_b  = (const float*)d_in[8];
    const float* root_w = (const float*)d_in[9];
    const float* pw1    = (const float*)d_in[10];
    const float* pb1    = (const float*)d_in[11];
    const float* pw2    = (const float*)d_in[12];
    const float* pb2    = (const float*)d_in[13];
    const float* cls_w  = (const float*)d_in[14];
    const float* cls_b  = (const float*)d_in[15];
    float* out = (float*)d_out;

    // Workspace (~41 MB): h 12.8 | hb 6.4 | agg 12.8 (aliases bedges 5) | slots 8 | misc 0.6
    char* ws = (char*)d_ws;
    size_t off = 0;
    auto alloc = [&](size_t bytes) -> void* {
        off = (off + 255) & ~(size_t)255;
        void* p = ws + off;
        off += bytes;
        return p;
    };
    float* h      = (float*)alloc((size_t)NN * HH * 4);
    u16*   hb     = (u16*)alloc((size_t)NN * HH * 2);
    float* agg    = (float*)alloc((size_t)NN * HH * 4);
    u32*   bedges = (u32*)agg;                       // alias: bedges dead before agg L0 write
    u16*   slots  = (u16*)alloc((size_t)NDP * MAXDEG * 2);
    int*   deg    = (int*)alloc((size_t)NDP * 4);
    int*   gboff  = (int*)alloc((size_t)SBLK * PBUK * 4);
    int*   ghist  = (int*)alloc((size_t)SBLK * PBUK * 4);

    // launch 1: embed (independent) + edge counting-sort, block-partitioned
    k_embed_psort<<<NTILES + SBLK, 256, 0, stream>>>(
        x, emb_w1, emb_b1, emb_w2, emb_b2, h, hb, ei, bedges, gboff, ghist);
    // launch 2: adjacency
    k_adj<<<PBUK, 256, 0, stream>>>(bedges, gboff, ghist, slots, deg);
    // layer 0
    k_agg<<<(NN + 7) / 8, 256, 0, stream>>>(hb, deg, slots, agg);
    k_dense<<<NTILES, 256, 0, stream>>>(h, agg, rel_w, rel_b, root_w,
                                        pw1, pb1, pw2, pb2, hb, 1);
    // layer 1
    k_agg<<<(NN + 7) / 8, 256, 0, stream>>>(hb, deg, slots, agg);
    k_dense<<<NTILES, 256, 0, stream>>>(h, agg,
                                        rel_w + HH * HH, rel_b + HH, root_w + HH * HH,
                                        pw1 + HH * HH, pb1 + HH, pw2 + HH * HH, pb2 + HH,
                                        hb, 0);
    // pooled mean + classifier
    k_poolcls<<<NG, 256, 0, stream>>>(h, batch, cls_w, cls_b, out);
}

// Round 18
// 311.539 us; speedup vs baseline: 3.0570x; 1.0771x over previous
//
#include <hip/hip_runtime.h>

typedef unsigned int u32;
typedef unsigned short u16;

#define NN 50000
#define EE 1250000
#define DD 128
#define HH 64
#define NCLS 10
#define NG 128
#define MAXDEG 80                    // Poisson(25): P(deg>=80) ~ 0

#define NTILES ((NN + 63) / 64)     // 782
#define LDSW 68                      // LDS row stride for GEMM tiles

#define PBUK 392                     // buckets = dst>>7
#define SBLK 128                     // sort chunks
#define CHUNK ((EE + SBLK - 1) / SBLK)  // 9766
#define NDP  (PBUK * 128)            // 50176

// Round-2: int inputs are int32. ei int32 [2,E]: src=ei[e], dst=ei[EE+e].
// Round-3: no ReLU between GraphConv out and post-MLP.
// Round-5/12: per-element device atomics serialize at the coherence point --
// pre-reduce per block, THEN few atomics (done right this round).
// Round-7..10: adjacency via per-block counting sort (full-line writes only).
// Round-14: don't fuse the latency-bound gather into the LDS-capped GEMM.
// Round-16: coop grid.sync() on 8 non-coherent XCDs = system-scope L2 flush -- never.
// Round-17: embed+psort merged (independent work, block-partitioned).
// Round-18: (a) iS column swizzle c^=k&60 -- transpose writes were 8-way bank
// conflicts (2M cycles/kernel); reader iS[k][ty*4] is a broadcast so any
// k-dependent column permutation is legal. (b) pool fused into dense-L1 via
// block pre-reduce + <=2 atomics/feature (100K atomics, 12-deep chains);
// dense-L1 drops h/hb stores; poolcls -> thin k_cls; pooled zeroed in k_adj.

__device__ __forceinline__ u32 f2bf(float f) {           // RNE fp32->bf16
    u32 u = __float_as_uint(f);
    return (u + 0x7FFFu + ((u >> 16) & 1u)) >> 16;
}
__device__ __forceinline__ float bf2f(u16 v) {
    return __uint_as_float(((u32)v) << 16);
}

// ---------------- tiled-GEMM building blocks (iS is column-swizzled) ----------------

__device__ __forceinline__ void load_w(const float* __restrict__ g, float (*wS)[LDSW], int t) {
    #pragma unroll
    for (int r = 0; r < 4; ++r) {
        int idx = r * 256 + t;
        int k = idx >> 4, f4 = idx & 15;
        float4 v = *(const float4*)(g + k * 64 + f4 * 4);
        *(float4*)&wS[k][f4 * 4] = v;
    }
}

__device__ __forceinline__ void load_inT(const float* __restrict__ g, int ld, int c0,
                                         float (*iS)[LDSW], int t, int nb) {
    #pragma unroll
    for (int r = 0; r < 4; ++r) {
        int idx = r * 256 + t;
        int n = idx >> 4, k4 = idx & 15;
        int node = nb + n;
        if (node >= NN) node = NN - 1;
        float4 v = *(const float4*)(g + (size_t)node * ld + c0 + k4 * 4);
        int k0 = k4 * 4;
        int nx = n ^ k0;               // swizzle: (k0+j)&60 == k0 for j<4
        iS[k0 + 0][nx] = v.x;
        iS[k0 + 1][nx] = v.y;
        iS[k0 + 2][nx] = v.z;
        iS[k0 + 3][nx] = v.w;
    }
}

__device__ __forceinline__ void gemm_acc(const float (*iS)[LDSW], const float (*wS)[LDSW],
                                         float acc[4][4], int tx, int ty) {
    #pragma unroll 8
    for (int k = 0; k < 64; ++k) {
        const float4 wv = *(const float4*)&wS[k][tx * 4];
        const float4 iv = *(const float4*)&iS[k][(ty * 4) ^ (k & 60)];   // broadcast read
        acc[0][0] += iv.x * wv.x; acc[0][1] += iv.x * wv.y; acc[0][2] += iv.x * wv.z; acc[0][3] += iv.x * wv.w;
        acc[1][0] += iv.y * wv.x; acc[1][1] += iv.y * wv.y; acc[1][2] += iv.y * wv.z; acc[1][3] += iv.y * wv.w;
        acc[2][0] += iv.z * wv.x; acc[2][1] += iv.z * wv.y; acc[2][2] += iv.z * wv.z; acc[2][3] += iv.z * wv.w;
        acc[3][0] += iv.w * wv.x; acc[3][1] += iv.w * wv.y; acc[3][2] += iv.w * wv.z; acc[3][3] += iv.w * wv.w;
    }
}

__device__ __forceinline__ void store_accT(float (*iS)[LDSW], const float acc[4][4], int tx, int ty) {
    #pragma unroll
    for (int i = 0; i < 4; ++i) {
        int k = tx * 4 + i;            // (k&60) == tx*4
        *(float4*)&iS[k][(ty * 4) ^ (tx * 4)] =
            make_float4(acc[0][i], acc[1][i], acc[2][i], acc[3][i]);
    }
}

__device__ __forceinline__ void init_bias(float acc[4][4], const float* __restrict__ b, int tx) {
    float4 bv = *(const float4*)(b + tx * 4);
    #pragma unroll
    for (int j = 0; j < 4; ++j) { acc[j][0] = bv.x; acc[j][1] = bv.y; acc[j][2] = bv.z; acc[j][3] = bv.w; }
}

__device__ __forceinline__ void relu_acc(float acc[4][4]) {
    #pragma unroll
    for (int j = 0; j < 4; ++j)
        #pragma unroll
        for (int i = 0; i < 4; ++i) acc[j][i] = fmaxf(acc[j][i], 0.0f);
}

__device__ __forceinline__ void store_out(float* __restrict__ g, const float acc[4][4],
                                          int tx, int ty, int nb) {
    #pragma unroll
    for (int j = 0; j < 4; ++j) {
        int node = nb + ty * 4 + j;
        if (node < NN)
            *(float4*)(g + (size_t)node * HH + tx * 4) =
                make_float4(acc[j][0], acc[j][1], acc[j][2], acc[j][3]);
    }
}

__device__ __forceinline__ void store_hb(u16* __restrict__ hb, const float acc[4][4],
                                         int tx, int ty, int nb) {
    #pragma unroll
    for (int j = 0; j < 4; ++j) {
        int node = nb + ty * 4 + j;
        if (node < NN) {
            u32 p0 = f2bf(acc[j][0]) | (f2bf(acc[j][1]) << 16);
            u32 p1 = f2bf(acc[j][2]) | (f2bf(acc[j][3]) << 16);
            u32* q = (u32*)(hb + (size_t)node * HH) + tx * 2;
            q[0] = p0; q[1] = p1;
        }
    }
}

// ---------------- merged launch 1: embed tiles + psort chunks (independent) ----------------

__global__ __launch_bounds__(256) void k_embed_psort(
    const float* __restrict__ x,
    const float* __restrict__ w1, const float* __restrict__ b1,
    const float* __restrict__ w2, const float* __restrict__ b2,
    float* __restrict__ h, u16* __restrict__ hb,
    const int* __restrict__ ei, u32* __restrict__ bedges,
    int* __restrict__ gboff, int* __restrict__ ghist) {
    __shared__ __align__(16) char smem[2 * 64 * LDSW * 4];   // 34816 B
    const int t = threadIdx.x;

    if (blockIdx.x < NTILES) {
        float (*wS)[LDSW] = (float (*)[LDSW])smem;
        float (*iS)[LDSW] = (float (*)[LDSW])(smem + 64 * LDSW * 4);
        const int tx = t & 15, ty = t >> 4;
        const int nb = blockIdx.x * 64;

        float acc[4][4];
        init_bias(acc, b1, tx);
        load_w(w1, wS, t);
        load_inT(x, DD, 0, iS, t, nb);
        __syncthreads();
        gemm_acc(iS, wS, acc, tx, ty);
        __syncthreads();
        load_w(w1 + 64 * 64, wS, t);
        load_inT(x, DD, 64, iS, t, nb);
        __syncthreads();
        gemm_acc(iS, wS, acc, tx, ty);
        __syncthreads();
        relu_acc(acc);
        store_accT(iS, acc, tx, ty);
        load_w(w2, wS, t);
        __syncthreads();
        float acc2[4][4];
        init_bias(acc2, b2, tx);
        gemm_acc(iS, wS, acc2, tx, ty);
        store_out(h, acc2, tx, ty, nb);
        store_hb(hb, acc2, tx, ty, nb);
    } else {
        int* hist  = (int*)smem;
        int* boffS = hist + PBUK;
        int* wsum  = boffS + PBUK;
        const int cb = blockIdx.x - NTILES;
        const int base = cb * CHUNK;
        const int n = min(CHUNK, EE - base);

        for (int b = t; b < PBUK; b += 256) hist[b] = 0;
        __syncthreads();
        for (int i = t; i < n; i += 256) {
            int src = ei[base + i];
            int dst = ei[EE + base + i];
            if ((unsigned)src < NN && (unsigned)dst < NN)
                atomicAdd(&hist[dst >> 7], 1);
        }
        __syncthreads();
        int v = 0, h0 = 0;
        if (t < PBUK / 2) { h0 = hist[2 * t]; v = h0 + hist[2 * t + 1]; }
        int lane = t & 63, wd = t >> 6;
        int incl = v;
        #pragma unroll
        for (int d = 1; d < 64; d <<= 1) {
            int tt = __shfl_up(incl, d);
            if (lane >= d) incl += tt;
        }
        if (lane == 63) wsum[wd] = incl;
        __syncthreads();
        int woff = 0;
        for (int w = 0; w < wd; ++w) woff += wsum[w];
        if (t < PBUK / 2) {
            int excl = woff + incl - v;
            boffS[2 * t] = excl;
            boffS[2 * t + 1] = excl + h0;
        }
        __syncthreads();
        for (int b = t; b < PBUK; b += 256) {
            gboff[cb * PBUK + b] = boffS[b];
            ghist[cb * PBUK + b] = hist[b];
        }
        __syncthreads();
        for (int b = t; b < PBUK; b += 256) hist[b] = 0;
        __syncthreads();
        for (int i = t; i < n; i += 256) {
            int src = ei[base + i];
            int dst = ei[EE + base + i];
            if ((unsigned)src < NN && (unsigned)dst < NN) {
                int b = dst >> 7;
                int p = atomicAdd(&hist[b], 1);
                bedges[base + boffS[b] + p] = ((u32)src << 7) | (u32)(dst & 127);
            }
        }
    }
}

// ---------------- adjacency build (+ zero pooled for the fused-pool epilogue) ----------------

__global__ __launch_bounds__(256) void k_adj(const u32* __restrict__ bedges,
                                             const int* __restrict__ gboff,
                                             const int* __restrict__ ghist,
                                             u16* __restrict__ slots,
                                             int* __restrict__ deg,
                                             float* __restrict__ pooled) {
    __shared__ u16 ls[128 * MAXDEG];   // 20 KB
    __shared__ int lc[128];
    const int b = blockIdx.x, t = threadIdx.x;
    const int lane = t & 63, wid = t >> 6;
    if (b < (NG * HH) / 256) pooled[b * 256 + t] = 0.0f;   // 32 blocks zero 8192 floats
    if (t < 128) lc[t] = 0;
    __syncthreads();
    for (int sb = wid; sb < SBLK; sb += 4) {
        int off = gboff[sb * PBUK + b];
        int cnt = ghist[sb * PBUK + b];
        int gbase = sb * CHUNK + off;
        for (int i = lane; i < cnt; i += 64) {
            u32 p = bedges[gbase + i];
            int o = (int)(p & 127u);
            int src = (int)(p >> 7);
            int pos = atomicAdd(&lc[o], 1);
            if (pos < MAXDEG) ls[o * MAXDEG + pos] = (u16)src;
        }
    }
    __syncthreads();
    u32* gs = (u32*)(slots + (size_t)b * 128 * MAXDEG);
    const u32* lsu = (const u32*)ls;
    for (int i = t; i < 128 * MAXDEG / 2; i += 256) gs[i] = lsu[i];
    if (t < 128) deg[b * 128 + t] = lc[t];
}

// ---------------- Mean aggregation: 2 nodes/wave, 16 gathers in flight ----------------

__global__ __launch_bounds__(256) void k_agg(
    const u16* __restrict__ hb, const int* __restrict__ deg,
    const u16* __restrict__ slots, float* __restrict__ agg) {
    const int wid = threadIdx.x >> 6, lane = threadIdx.x & 63;
    const int nA = blockIdx.x * 8 + wid * 2;
    if (nA >= NN) return;
    const int nB = nA + 1;
    const int dA = deg[nA];
    const int dB = (nB < NN) ? deg[nB] : 0;
    const int mA = min(dA, MAXDEG), mB = min(dB, MAXDEG);
    const u16* srA = slots + (size_t)nA * MAXDEG;
    const u16* srB = slots + (size_t)nB * MAXDEG;
    const u32* rowA = (const u32*)srA;
    const u32* rowB = (const u32*)srB;
    float sA = 0.0f, sB = 0.0f;
    const int mm = max(mA, mB);
    for (int e = 0; e + 8 <= mm; e += 8) {
        const int hx = e >> 1;
        const bool pA = (e + 8 <= mA), pB = (e + 8 <= mB);   // wave-uniform
        float a0=0,a1=0,a2=0,a3=0,a4=0,a5=0,a6=0,a7=0;
        float b0=0,b1=0,b2=0,b3=0,b4=0,b5=0,b6=0,b7=0;
        if (pA) {
            u32 u0 = rowA[hx], u1 = rowA[hx+1], u2 = rowA[hx+2], u3 = rowA[hx+3];
            a0 = bf2f(hb[(size_t)(u0 & 0xffffu) * HH + lane]);
            a1 = bf2f(hb[(size_t)(u0 >> 16) * HH + lane]);
            a2 = bf2f(hb[(size_t)(u1 & 0xffffu) * HH + lane]);
            a3 = bf2f(hb[(size_t)(u1 >> 16) * HH + lane]);
            a4 = bf2f(hb[(size_t)(u2 & 0xffffu) * HH + lane]);
            a5 = bf2f(hb[(size_t)(u2 >> 16) * HH + lane]);
            a6 = bf2f(hb[(size_t)(u3 & 0xffffu) * HH + lane]);
            a7 = bf2f(hb[(size_t)(u3 >> 16) * HH + lane]);
        }
        if (pB) {
            u32 u0 = rowB[hx], u1 = rowB[hx+1], u2 = rowB[hx+2], u3 = rowB[hx+3];
            b0 = bf2f(hb[(size_t)(u0 & 0xffffu) * HH + lane]);
            b1 = bf2f(hb[(size_t)(u0 >> 16) * HH + lane]);
            b2 = bf2f(hb[(size_t)(u1 & 0xffffu) * HH + lane]);
            b3 = bf2f(hb[(size_t)(u1 >> 16) * HH + lane]);
            b4 = bf2f(hb[(size_t)(u2 & 0xffffu) * HH + lane]);
            b5 = bf2f(hb[(size_t)(u2 >> 16) * HH + lane]);
            b6 = bf2f(hb[(size_t)(u3 & 0xffffu) * HH + lane]);
            b7 = bf2f(hb[(size_t)(u3 >> 16) * HH + lane]);
        }
        if (pA) sA += ((a0 + a1) + (a2 + a3)) + ((a4 + a5) + (a6 + a7));
        if (pB) sB += ((b0 + b1) + (b2 + b3)) + ((b4 + b5) + (b6 + b7));
    }
    for (int e = mA & ~7; e < mA; ++e)
        sA += bf2f(hb[(size_t)srA[e] * HH + lane]);
    for (int e = mB & ~7; e < mB; ++e)
        sB += bf2f(hb[(size_t)srB[e] * HH + lane]);
    agg[(size_t)nA * HH + lane] = sA * (1.0f / (float)max(dA, 1));
    if (nB < NN)
        agg[(size_t)nB * HH + lane] = sB * (1.0f / (float)max(dB, 1));
}

// ---------------- Dense per-layer; L1 variant fuses block-pre-reduced pooling ----------------

__global__ __launch_bounds__(256) void k_dense(
    float* __restrict__ h, const float* __restrict__ agg,
    const float* __restrict__ relw, const float* __restrict__ relb,
    const float* __restrict__ rootw,
    const float* __restrict__ pw1, const float* __restrict__ pb1,
    const float* __restrict__ pw2, const float* __restrict__ pb2,
    u16* __restrict__ hb, int do_hb,
    const int* __restrict__ batch, float* __restrict__ pooled, int do_pool) {
    __shared__ float wS[64][LDSW];
    __shared__ float iS[64][LDSW];
    const int t = threadIdx.x;
    const int tx = t & 15, ty = t >> 4;
    const int nb = blockIdx.x * 64;

    float acc[4][4];
    init_bias(acc, relb, tx);

    load_w(relw, wS, t);
    load_inT(agg, HH, 0, iS, t, nb);
    __syncthreads();
    gemm_acc(iS, wS, acc, tx, ty);
    __syncthreads();
    load_w(rootw, wS, t);
    load_inT(h, HH, 0, iS, t, nb);
    __syncthreads();
    gemm_acc(iS, wS, acc, tx, ty);
    __syncthreads();
    store_accT(iS, acc, tx, ty);
    load_w(pw1, wS, t);
    __syncthreads();
    float acc2[4][4];
    init_bias(acc2, pb1, tx);
    gemm_acc(iS, wS, acc2, tx, ty);
    relu_acc(acc2);
    __syncthreads();
    store_accT(iS, acc2, tx, ty);
    load_w(pw2, wS, t);
    __syncthreads();
    float acc3[4][4];
    init_bias(acc3, pb2, tx);
    gemm_acc(iS, wS, acc3, tx, ty);
    relu_acc(acc3);

    if (!do_pool) {
        store_out(h, acc3, tx, ty, nb);
        if (do_hb) store_hb(hb, acc3, tx, ty, nb);
    } else {
        // fused mean-pool numerator: pre-reduce this block's 64 nodes in LDS,
        // then <=few atomics per feature (nodes sorted by group).
        __syncthreads();
        store_accT(iS, acc3, tx, ty);          // iS[feat][node] (swizzled)
        __syncthreads();
        if (t < HH) {
            const int f = t;
            const int fs = f & 60;             // row swizzle constant
            const int n1 = min(64, NN - nb);
            int cur = batch[nb];
            float s = 0.0f;
            for (int i = 0; i < n1; ++i) {
                int g = batch[nb + i];         // sorted; broadcast read
                if (g != cur) {
                    if ((unsigned)cur < NG) atomicAdd(&pooled[cur * HH + f], s);
                    s = 0.0f; cur = g;
                }
                s += iS[f][i ^ fs];
            }
            if ((unsigned)cur < NG) atomicAdd(&pooled[cur * HH + f], s);
        }
    }
}

// ---------------- classifier (pooled sums -> mean -> linear) ----------------

__global__ void k_cls(const float* __restrict__ pooled, const int* __restrict__ batch,
                      const float* __restrict__ w, const float* __restrict__ b,
                      float* __restrict__ out) {
    const int g = blockIdx.x;
    const int t = threadIdx.x;
    if (t >= NCLS) return;
    int lo = 0, hi = NN;
    while (lo < hi) { int mid = (lo + hi) >> 1; if (batch[mid] < g) lo = mid + 1; else hi = mid; }
    const int beg = lo;
    lo = 0; hi = NN;
    while (lo < hi) { int mid = (lo + hi) >> 1; if (batch[mid] < g + 1) lo = mid + 1; else hi = mid; }
    const int cnt = lo - beg;
    const float inv = 1.0f / (float)max(cnt, 1);
    float o = b[t];
    #pragma unroll 8
    for (int k = 0; k < HH; ++k) o += pooled[g * HH + k] * inv * w[k * NCLS + t];
    out[g * NCLS + t] = o;
}

// ---------------- Launch ----------------

extern "C" void kernel_launch(void* const* d_in, const int* in_sizes, int n_in,
                              void* d_out, int out_size, void* d_ws, size_t ws_size,
                              hipStream_t stream) {
    const float* x      = (const float*)d_in[0];
    const int*   ei     = (const int*)d_in[1];    // int32 [2,E]
    const int*   batch  = (const int*)d_in[2];    // int32 [N], sorted
    const float* emb_w1 = (const float*)d_in[3];
    const float* emb_b1 = (const float*)d_in[4];
    const float* emb_w2 = (const float*)d_in[5];
    const float* emb_b2 = (const float*)d_in[6];
    const float* rel_w  = (const float*)d_in[7];
    const float* rel_b  = (const float*)d_in[8];
    const float* root_w = (const float*)d_in[9];
    const float* pw1    = (const float*)d_in[10];
    const float* pb1    = (const float*)d_in[11];
    const float* pw2    = (const float*)d_in[12];
    const float* pb2    = (const float*)d_in[13];
    const float* cls_w  = (const float*)d_in[14];
    const float* cls_b  = (const float*)d_in[15];
    float* out = (float*)d_out;

    // Workspace (~41 MB): h 12.8 | hb 6.4 | agg 12.8 (aliases bedges 5) | slots 8 | misc 0.6
    char* ws = (char*)d_ws;
    size_t off = 0;
    auto alloc = [&](size_t bytes) -> void* {
        off = (off + 255) & ~(size_t)255;
        void* p = ws + off;
        off += bytes;
        return p;
    };
    float* h      = (float*)alloc((size_t)NN * HH * 4);
    u16*   hb     = (u16*)alloc((size_t)NN * HH * 2);
    float* agg    = (float*)alloc((size_t)NN * HH * 4);
    u32*   bedges = (u32*)agg;                       // alias: bedges dead before agg L0 write
    u16*   slots  = (u16*)alloc((size_t)NDP * MAXDEG * 2);
    int*   deg    = (int*)alloc((size_t)NDP * 4);
    int*   gboff  = (int*)alloc((size_t)SBLK * PBUK * 4);
    int*   ghist  = (int*)alloc((size_t)SBLK * PBUK * 4);
    float* pooled = (float*)alloc((size_t)NG * HH * 4);

    // launch 1: embed (independent) + edge counting-sort, block-partitioned
    k_embed_psort<<<NTILES + SBLK, 256, 0, stream>>>(
        x, emb_w1, emb_b1, emb_w2, emb_b2, h, hb, ei, bedges, gboff, ghist);
    // launch 2: adjacency (+ zero pooled)
    k_adj<<<PBUK, 256, 0, stream>>>(bedges, gboff, ghist, slots, deg, pooled);
    // layer 0
    k_agg<<<(NN + 7) / 8, 256, 0, stream>>>(hb, deg, slots, agg);
    k_dense<<<NTILES, 256, 0, stream>>>(h, agg, rel_w, rel_b, root_w,
                                        pw1, pb1, pw2, pb2, hb, 1,
                                        batch, pooled, 0);
    // layer 1 (fused block-pre-reduced pooling; no h/hb stores)
    k_agg<<<(NN + 7) / 8, 256, 0, stream>>>(hb, deg, slots, agg);
    k_dense<<<NTILES, 256, 0, stream>>>(h, agg,
                                        rel_w + HH * HH, rel_b + HH, root_w + HH * HH,
                                        pw1 + HH * HH, pb1 + HH, pw2 + HH * HH, pb2 + HH,
                                        hb, 0,
                                        batch, pooled, 1);
    // classifier
    k_cls<<<NG, 64, 0, stream>>>(pooled, batch, cls_w, cls_b, out);
}

// Round 19
// 308.765 us; speedup vs baseline: 3.0845x; 1.0090x over previous
//
#include <hip/hip_runtime.h>

typedef unsigned int u32;
typedef unsigned short u16;

#define NN 50000
#define EE 1250000
#define DD 128
#define HH 64
#define NCLS 10
#define NG 128
#define MAXDEG 80                    // Poisson(25): P(deg>=80) ~ 0

#define NTILES ((NN + 63) / 64)     // 782
#define LDSW 68                      // LDS row stride for GEMM tiles

#define PBUK 392                     // buckets = dst>>7
#define SBLK 128                     // sort chunks
#define CHUNK ((EE + SBLK - 1) / SBLK)  // 9766
#define NDP  (PBUK * 128)            // 50176

// Round-2: int inputs are int32. ei int32 [2,E]: src=ei[e], dst=ei[EE+e].
// Round-3: no ReLU between GraphConv out and post-MLP.
// Round-5/12/18: atomics only after block pre-reduction.
// Round-7..10: adjacency via per-block counting sort (full-line writes only).
// Round-14: keep the latency-bound gather in its own high-occupancy kernel.
// Round-16: no coop grid.sync() on 8 non-coherent XCDs (system-scope L2 flush).
// Round-17: embed+psort merged. Round-18: iS XOR column swizzle (conflicts 2M->0.5M),
// pool fused into dense-L1 (pre-reduce + few atomics).
// Round-19: DROP the fp32 h buffer entirely -- the root term now reads the bf16
// shadow hb (51 MB of HBM traffic removed); dense-L0 is in-place on hb.
// Numerics: second bf16-rounded branch -> absmax ~1.5e-5 -> ~2-3e-5 (thr 6.35e-5).

__device__ __forceinline__ u32 f2bf(float f) {           // RNE fp32->bf16
    u32 u = __float_as_uint(f);
    return (u + 0x7FFFu + ((u >> 16) & 1u)) >> 16;
}
__device__ __forceinline__ float bf2f(u16 v) {
    return __uint_as_float(((u32)v) << 16);
}

// ---------------- tiled-GEMM building blocks (iS is column-swizzled: col = n ^ (k&60)) ----------------

__device__ __forceinline__ void load_w(const float* __restrict__ g, float (*wS)[LDSW], int t) {
    #pragma unroll
    for (int r = 0; r < 4; ++r) {
        int idx = r * 256 + t;
        int k = idx >> 4, f4 = idx & 15;
        float4 v = *(const float4*)(g + k * 64 + f4 * 4);
        *(float4*)&wS[k][f4 * 4] = v;
    }
}

__device__ __forceinline__ void load_inT(const float* __restrict__ g, int ld, int c0,
                                         float (*iS)[LDSW], int t, int nb) {
    #pragma unroll
    for (int r = 0; r < 4; ++r) {
        int idx = r * 256 + t;
        int n = idx >> 4, k4 = idx & 15;
        int node = nb + n;
        if (node >= NN) node = NN - 1;
        float4 v = *(const float4*)(g + (size_t)node * ld + c0 + k4 * 4);
        int k0 = k4 * 4;
        int nx = n ^ k0;               // (k0+j)&60 == k0 for j<4
        iS[k0 + 0][nx] = v.x;
        iS[k0 + 1][nx] = v.y;
        iS[k0 + 2][nx] = v.z;
        iS[k0 + 3][nx] = v.w;
    }
}

// bf16 variant: root-term load from the hb shadow (coalesced uint4, 8 feats/thread)
__device__ __forceinline__ void load_inT_hb(const u16* __restrict__ g,
                                            float (*iS)[LDSW], int t, int nb) {
    #pragma unroll
    for (int r = 0; r < 2; ++r) {
        int idx = r * 256 + t;         // 0..511
        int n = idx >> 3, c = idx & 7; // node, 16B-chunk (8 feats)
        int node = nb + n;
        if (node >= NN) node = NN - 1;
        uint4 v = *(const uint4*)(g + (size_t)node * HH + c * 8);
        int k0 = c * 8;
        int nx1 = n ^ k0;              // feats k0..k0+3: (k&60)==k0
        int nx2 = n ^ (k0 + 4);        // feats k0+4..k0+7
        iS[k0 + 0][nx1] = bf2f((u16)(v.x & 0xffffu));
        iS[k0 + 1][nx1] = bf2f((u16)(v.x >> 16));
        iS[k0 + 2][nx1] = bf2f((u16)(v.y & 0xffffu));
        iS[k0 + 3][nx1] = bf2f((u16)(v.y >> 16));
        iS[k0 + 4][nx2] = bf2f((u16)(v.z & 0xffffu));
        iS[k0 + 5][nx2] = bf2f((u16)(v.z >> 16));
        iS[k0 + 6][nx2] = bf2f((u16)(v.w & 0xffffu));
        iS[k0 + 7][nx2] = bf2f((u16)(v.w >> 16));
    }
}

__device__ __forceinline__ void gemm_acc(const float (*iS)[LDSW], const float (*wS)[LDSW],
                                         float acc[4][4], int tx, int ty) {
    #pragma unroll 8
    for (int k = 0; k < 64; ++k) {
        const float4 wv = *(const float4*)&wS[k][tx * 4];
        const float4 iv = *(const float4*)&iS[k][(ty * 4) ^ (k & 60)];   // broadcast read
        acc[0][0] += iv.x * wv.x; acc[0][1] += iv.x * wv.y; acc[0][2] += iv.x * wv.z; acc[0][3] += iv.x * wv.w;
        acc[1][0] += iv.y * wv.x; acc[1][1] += iv.y * wv.y; acc[1][2] += iv.y * wv.z; acc[1][3] += iv.y * wv.w;
        acc[2][0] += iv.z * wv.x; acc[2][1] += iv.z * wv.y; acc[2][2] += iv.z * wv.z; acc[2][3] += iv.z * wv.w;
        acc[3][0] += iv.w * wv.x; acc[3][1] += iv.w * wv.y; acc[3][2] += iv.w * wv.z; acc[3][3] += iv.w * wv.w;
    }
}

__device__ __forceinline__ void store_accT(float (*iS)[LDSW], const float acc[4][4], int tx, int ty) {
    #pragma unroll
    for (int i = 0; i < 4; ++i) {
        int k = tx * 4 + i;            // (k&60) == tx*4
        *(float4*)&iS[k][(ty * 4) ^ (tx * 4)] =
            make_float4(acc[0][i], acc[1][i], acc[2][i], acc[3][i]);
    }
}

__device__ __forceinline__ void init_bias(float acc[4][4], const float* __restrict__ b, int tx) {
    float4 bv = *(const float4*)(b + tx * 4);
    #pragma unroll
    for (int j = 0; j < 4; ++j) { acc[j][0] = bv.x; acc[j][1] = bv.y; acc[j][2] = bv.z; acc[j][3] = bv.w; }
}

__device__ __forceinline__ void relu_acc(float acc[4][4]) {
    #pragma unroll
    for (int j = 0; j < 4; ++j)
        #pragma unroll
        for (int i = 0; i < 4; ++i) acc[j][i] = fmaxf(acc[j][i], 0.0f);
}

__device__ __forceinline__ void store_hb(u16* __restrict__ hb, const float acc[4][4],
                                         int tx, int ty, int nb) {
    #pragma unroll
    for (int j = 0; j < 4; ++j) {
        int node = nb + ty * 4 + j;
        if (node < NN) {
            u32 p0 = f2bf(acc[j][0]) | (f2bf(acc[j][1]) << 16);
            u32 p1 = f2bf(acc[j][2]) | (f2bf(acc[j][3]) << 16);
            u32* q = (u32*)(hb + (size_t)node * HH) + tx * 2;
            q[0] = p0; q[1] = p1;
        }
    }
}

// ---------------- merged launch 1: embed tiles + psort chunks (independent) ----------------

__global__ __launch_bounds__(256) void k_embed_psort(
    const float* __restrict__ x,
    const float* __restrict__ w1, const float* __restrict__ b1,
    const float* __restrict__ w2, const float* __restrict__ b2,
    u16* __restrict__ hb,
    const int* __restrict__ ei, u32* __restrict__ bedges,
    int* __restrict__ gboff, int* __restrict__ ghist) {
    __shared__ __align__(16) char smem[2 * 64 * LDSW * 4];   // 34816 B
    const int t = threadIdx.x;

    if (blockIdx.x < NTILES) {
        float (*wS)[LDSW] = (float (*)[LDSW])smem;
        float (*iS)[LDSW] = (float (*)[LDSW])(smem + 64 * LDSW * 4);
        const int tx = t & 15, ty = t >> 4;
        const int nb = blockIdx.x * 64;

        float acc[4][4];
        init_bias(acc, b1, tx);
        load_w(w1, wS, t);
        load_inT(x, DD, 0, iS, t, nb);
        __syncthreads();
        gemm_acc(iS, wS, acc, tx, ty);
        __syncthreads();
        load_w(w1 + 64 * 64, wS, t);
        load_inT(x, DD, 64, iS, t, nb);
        __syncthreads();
        gemm_acc(iS, wS, acc, tx, ty);
        __syncthreads();
        relu_acc(acc);
        store_accT(iS, acc, tx, ty);
        load_w(w2, wS, t);
        __syncthreads();
        float acc2[4][4];
        init_bias(acc2, b2, tx);
        gemm_acc(iS, wS, acc2, tx, ty);
        store_hb(hb, acc2, tx, ty, nb);          // bf16 shadow only; fp32 h eliminated
    } else {
        int* hist  = (int*)smem;
        int* boffS = hist + PBUK;
        int* wsum  = boffS + PBUK;
        const int cb = blockIdx.x - NTILES;
        const int base = cb * CHUNK;
        const int n = min(CHUNK, EE - base);

        for (int b = t; b < PBUK; b += 256) hist[b] = 0;
        __syncthreads();
        for (int i = t; i < n; i += 256) {
            int src = ei[base + i];
            int dst = ei[EE + base + i];
            if ((unsigned)src < NN && (unsigned)dst < NN)
                atomicAdd(&hist[dst >> 7], 1);
        }
        __syncthreads();
        int v = 0, h0 = 0;
        if (t < PBUK / 2) { h0 = hist[2 * t]; v = h0 + hist[2 * t + 1]; }
        int lane = t & 63, wd = t >> 6;
        int incl = v;
        #pragma unroll
        for (int d = 1; d < 64; d <<= 1) {
            int tt = __shfl_up(incl, d);
            if (lane >= d) incl += tt;
        }
        if (lane == 63) wsum[wd] = incl;
        __syncthreads();
        int woff = 0;
        for (int w = 0; w < wd; ++w) woff += wsum[w];
        if (t < PBUK / 2) {
            int excl = woff + incl - v;
            boffS[2 * t] = excl;
            boffS[2 * t + 1] = excl + h0;
        }
        __syncthreads();
        for (int b = t; b < PBUK; b += 256) {
            gboff[cb * PBUK + b] = boffS[b];
            ghist[cb * PBUK + b] = hist[b];
        }
        __syncthreads();
        for (int b = t; b < PBUK; b += 256) hist[b] = 0;
        __syncthreads();
        for (int i = t; i < n; i += 256) {
            int src = ei[base + i];
            int dst = ei[EE + base + i];
            if ((unsigned)src < NN && (unsigned)dst < NN) {
                int b = dst >> 7;
                int p = atomicAdd(&hist[b], 1);
                bedges[base + boffS[b] + p] = ((u32)src << 7) | (u32)(dst & 127);
            }
        }
    }
}

// ---------------- adjacency build (+ zero pooled for the fused-pool epilogue) ----------------

__global__ __launch_bounds__(256) void k_adj(const u32* __restrict__ bedges,
                                             const int* __restrict__ gboff,
                                             const int* __restrict__ ghist,
                                             u16* __restrict__ slots,
                                             int* __restrict__ deg,
                                             float* __restrict__ pooled) {
    __shared__ u16 ls[128 * MAXDEG];   // 20 KB
    __shared__ int lc[128];
    const int b = blockIdx.x, t = threadIdx.x;
    const int lane = t & 63, wid = t >> 6;
    if (b < (NG * HH) / 256) pooled[b * 256 + t] = 0.0f;
    if (t < 128) lc[t] = 0;
    __syncthreads();
    for (int sb = wid; sb < SBLK; sb += 4) {
        int off = gboff[sb * PBUK + b];
        int cnt = ghist[sb * PBUK + b];
        int gbase = sb * CHUNK + off;
        for (int i = lane; i < cnt; i += 64) {
            u32 p = bedges[gbase + i];
            int o = (int)(p & 127u);
            int src = (int)(p >> 7);
            int pos = atomicAdd(&lc[o], 1);
            if (pos < MAXDEG) ls[o * MAXDEG + pos] = (u16)src;
        }
    }
    __syncthreads();
    u32* gs = (u32*)(slots + (size_t)b * 128 * MAXDEG);
    const u32* lsu = (const u32*)ls;
    for (int i = t; i < 128 * MAXDEG / 2; i += 256) gs[i] = lsu[i];
    if (t < 128) deg[b * 128 + t] = lc[t];
}

// ---------------- Mean aggregation: 2 nodes/wave, 16 gathers in flight ----------------

__global__ __launch_bounds__(256) void k_agg(
    const u16* __restrict__ hb, const int* __restrict__ deg,
    const u16* __restrict__ slots, float* __restrict__ agg) {
    const int wid = threadIdx.x >> 6, lane = threadIdx.x & 63;
    const int nA = blockIdx.x * 8 + wid * 2;
    if (nA >= NN) return;
    const int nB = nA + 1;
    const int dA = deg[nA];
    const int dB = (nB < NN) ? deg[nB] : 0;
    const int mA = min(dA, MAXDEG), mB = min(dB, MAXDEG);
    const u16* srA = slots + (size_t)nA * MAXDEG;
    const u16* srB = slots + (size_t)nB * MAXDEG;
    const u32* rowA = (const u32*)srA;
    const u32* rowB = (const u32*)srB;
    float sA = 0.0f, sB = 0.0f;
    const int mm = max(mA, mB);
    for (int e = 0; e + 8 <= mm; e += 8) {
        const int hx = e >> 1;
        const bool pA = (e + 8 <= mA), pB = (e + 8 <= mB);   // wave-uniform
        float a0=0,a1=0,a2=0,a3=0,a4=0,a5=0,a6=0,a7=0;
        float b0=0,b1=0,b2=0,b3=0,b4=0,b5=0,b6=0,b7=0;
        if (pA) {
            u32 u0 = rowA[hx], u1 = rowA[hx+1], u2 = rowA[hx+2], u3 = rowA[hx+3];
            a0 = bf2f(hb[(size_t)(u0 & 0xffffu) * HH + lane]);
            a1 = bf2f(hb[(size_t)(u0 >> 16) * HH + lane]);
            a2 = bf2f(hb[(size_t)(u1 & 0xffffu) * HH + lane]);
            a3 = bf2f(hb[(size_t)(u1 >> 16) * HH + lane]);
            a4 = bf2f(hb[(size_t)(u2 & 0xffffu) * HH + lane]);
            a5 = bf2f(hb[(size_t)(u2 >> 16) * HH + lane]);
            a6 = bf2f(hb[(size_t)(u3 & 0xffffu) * HH + lane]);
            a7 = bf2f(hb[(size_t)(u3 >> 16) * HH + lane]);
        }
        if (pB) {
            u32 u0 = rowB[hx], u1 = rowB[hx+1], u2 = rowB[hx+2], u3 = rowB[hx+3];
            b0 = bf2f(hb[(size_t)(u0 & 0xffffu) * HH + lane]);
            b1 = bf2f(hb[(size_t)(u0 >> 16) * HH + lane]);
            b2 = bf2f(hb[(size_t)(u1 & 0xffffu) * HH + lane]);
            b3 = bf2f(hb[(size_t)(u1 >> 16) * HH + lane]);
            b4 = bf2f(hb[(size_t)(u2 & 0xffffu) * HH + lane]);
            b5 = bf2f(hb[(size_t)(u2 >> 16) * HH + lane]);
            b6 = bf2f(hb[(size_t)(u3 & 0xffffu) * HH + lane]);
            b7 = bf2f(hb[(size_t)(u3 >> 16) * HH + lane]);
        }
        if (pA) sA += ((a0 + a1) + (a2 + a3)) + ((a4 + a5) + (a6 + a7));
        if (pB) sB += ((b0 + b1) + (b2 + b3)) + ((b4 + b5) + (b6 + b7));
    }
    for (int e = mA & ~7; e < mA; ++e)
        sA += bf2f(hb[(size_t)srA[e] * HH + lane]);
    for (int e = mB & ~7; e < mB; ++e)
        sB += bf2f(hb[(size_t)srB[e] * HH + lane]);
    agg[(size_t)nA * HH + lane] = sA * (1.0f / (float)max(dA, 1));
    if (nB < NN)
        agg[(size_t)nB * HH + lane] = sB * (1.0f / (float)max(dB, 1));
}

// ---------------- Dense per-layer; root term from hb; L1 fuses pre-reduced pooling ----------------

__global__ __launch_bounds__(256) void k_dense(
    u16* hb, const float* __restrict__ agg,
    const float* __restrict__ relw, const float* __restrict__ relb,
    const float* __restrict__ rootw,
    const float* __restrict__ pw1, const float* __restrict__ pb1,
    const float* __restrict__ pw2, const float* __restrict__ pb2,
    const int* __restrict__ batch, float* __restrict__ pooled, int do_pool) {
    __shared__ float wS[64][LDSW];
    __shared__ float iS[64][LDSW];
    const int t = threadIdx.x;
    const int tx = t & 15, ty = t >> 4;
    const int nb = blockIdx.x * 64;

    float acc[4][4];
    init_bias(acc, relb, tx);

    load_w(relw, wS, t);
    load_inT(agg, HH, 0, iS, t, nb);
    __syncthreads();
    gemm_acc(iS, wS, acc, tx, ty);
    __syncthreads();
    load_w(rootw, wS, t);
    load_inT_hb(hb, iS, t, nb);          // root term from bf16 shadow (own rows)
    __syncthreads();
    gemm_acc(iS, wS, acc, tx, ty);
    __syncthreads();
    store_accT(iS, acc, tx, ty);
    load_w(pw1, wS, t);
    __syncthreads();
    float acc2[4][4];
    init_bias(acc2, pb1, tx);
    gemm_acc(iS, wS, acc2, tx, ty);
    relu_acc(acc2);
    __syncthreads();
    store_accT(iS, acc2, tx, ty);
    load_w(pw2, wS, t);
    __syncthreads();
    float acc3[4][4];
    init_bias(acc3, pb2, tx);
    gemm_acc(iS, wS, acc3, tx, ty);
    relu_acc(acc3);

    if (!do_pool) {
        store_hb(hb, acc3, tx, ty, nb);  // in-place: own rows only (read done at stage 2)
    } else {
        // fused mean-pool numerator: pre-reduce 64 nodes in LDS, few atomics/feature
        __syncthreads();
        store_accT(iS, acc3, tx, ty);
        __syncthreads();
        if (t < HH) {
            const int f = t;
            const int fs = f & 60;
            const int n1 = min(64, NN - nb);
            int cur = batch[nb];
            float s = 0.0f;
            for (int i = 0; i < n1; ++i) {
                int g = batch[nb + i];   // sorted; broadcast read
                if (g != cur) {
                    if ((unsigned)cur < NG) atomicAdd(&pooled[cur * HH + f], s);
                    s = 0.0f; cur = g;
                }
                s += iS[f][i ^ fs];
            }
            if ((unsigned)cur < NG) atomicAdd(&pooled[cur * HH + f], s);
        }
    }
}

// ---------------- classifier (pooled sums -> mean -> linear) ----------------

__global__ void k_cls(const float* __restrict__ pooled, const int* __restrict__ batch,
                      const float* __restrict__ w, const float* __restrict__ b,
                      float* __restrict__ out) {
    const int g = blockIdx.x;
    const int t = threadIdx.x;
    if (t >= NCLS) return;
    int lo = 0, hi = NN;
    while (lo < hi) { int mid = (lo + hi) >> 1; if (batch[mid] < g) lo = mid + 1; else hi = mid; }
    const int beg = lo;
    lo = 0; hi = NN;
    while (lo < hi) { int mid = (lo + hi) >> 1; if (batch[mid] < g + 1) lo = mid + 1; else hi = mid; }
    const int cnt = lo - beg;
    const float inv = 1.0f / (float)max(cnt, 1);
    float o = b[t];
    #pragma unroll 8
    for (int k = 0; k < HH; ++k) o += pooled[g * HH + k] * inv * w[k * NCLS + t];
    out[g * NCLS + t] = o;
}

// ---------------- Launch ----------------

extern "C" void kernel_launch(void* const* d_in, const int* in_sizes, int n_in,
                              void* d_out, int out_size, void* d_ws, size_t ws_size,
                              hipStream_t stream) {
    const float* x      = (const float*)d_in[0];
    const int*   ei     = (const int*)d_in[1];    // int32 [2,E]
    const int*   batch  = (const int*)d_in[2];    // int32 [N], sorted
    const float* emb_w1 = (const float*)d_in[3];
    const float* emb_b1 = (const float*)d_in[4];
    const float* emb_w2 = (const float*)d_in[5];
    const float* emb_b2 = (const float*)d_in[6];
    const float* rel_w  = (const float*)d_in[7];
    const float* rel_b  = (const float*)d_in[8];
    const float* root_w = (const float*)d_in[9];
    const float* pw1    = (const float*)d_in[10];
    const float* pb1    = (const float*)d_in[11];
    const float* pw2    = (const float*)d_in[12];
    const float* pb2    = (const float*)d_in[13];
    const float* cls_w  = (const float*)d_in[14];
    const float* cls_b  = (const float*)d_in[15];
    float* out = (float*)d_out;

    // Workspace (~28 MB): hb 6.4 | agg 12.8 (aliases bedges 5) | slots 8 | misc 0.6
    char* ws = (char*)d_ws;
    size_t off = 0;
    auto alloc = [&](size_t bytes) -> void* {
        off = (off + 255) & ~(size_t)255;
        void* p = ws + off;
        off += bytes;
        return p;
    };
    u16*   hb     = (u16*)alloc((size_t)NN * HH * 2);
    float* agg    = (float*)alloc((size_t)NN * HH * 4);
    u32*   bedges = (u32*)agg;                       // alias: bedges dead before agg L0 write
    u16*   slots  = (u16*)alloc((size_t)NDP * MAXDEG * 2);
    int*   deg    = (int*)alloc((size_t)NDP * 4);
    int*   gboff  = (int*)alloc((size_t)SBLK * PBUK * 4);
    int*   ghist  = (int*)alloc((size_t)SBLK * PBUK * 4);
    float* pooled = (float*)alloc((size_t)NG * HH * 4);

    // launch 1: embed (independent) + edge counting-sort, block-partitioned
    k_embed_psort<<<NTILES + SBLK, 256, 0, stream>>>(
        x, emb_w1, emb_b1, emb_w2, emb_b2, hb, ei, bedges, gboff, ghist);
    // launch 2: adjacency (+ zero pooled)
    k_adj<<<PBUK, 256, 0, stream>>>(bedges, gboff, ghist, slots, deg, pooled);
    // layer 0 (dense in-place on hb)
    k_agg<<<(NN + 7) / 8, 256, 0, stream>>>(hb, deg, slots, agg);
    k_dense<<<NTILES, 256, 0, stream>>>(hb, agg, rel_w, rel_b, root_w,
                                        pw1, pb1, pw2, pb2, batch, pooled, 0);
    // layer 1 (fused block-pre-reduced pooling; no hb store)
    k_agg<<<(NN + 7) / 8, 256, 0, stream>>>(hb, deg, slots, agg);
    k_dense<<<NTILES, 256, 0, stream>>>(hb, agg,
                                        rel_w + HH * HH, rel_b + HH, root_w + HH * HH,
                                        pw1 + HH * HH, pb1 + HH, pw2 + HH * HH, pb2 + HH,
                                        batch, pooled, 1);
    // classifier
    k_cls<<<NG, 64, 0, stream>>>(pooled, batch, cls_w, cls_b, out);
}